// Round 8
// baseline (480.175 us; speedup 1.0000x reference)
//
#include <hip/hip_runtime.h>

#define EDIM 64
#define HDIM 64
#define S_SIG  (-1.4426950408889634f)
#define S_TANH ( 2.8853900817779268f)
#define UPW 8     // users per wave (8 -> 2048 waves -> 2 waves/SIMD)

typedef short bf16x8 __attribute__((ext_vector_type(8)));
typedef float f32x4  __attribute__((ext_vector_type(4)));

__device__ __forceinline__ float rcp_(float x){ return __builtin_amdgcn_rcpf(x); }
__device__ __forceinline__ float exp2_(float x){ return __builtin_amdgcn_exp2f(x); }
__device__ __forceinline__ unsigned short f2bf(float f) {   // RNE
    unsigned int u = __float_as_uint(f);
    return (unsigned short)((u + 0x7FFF + ((u >> 16) & 1)) >> 16);
}
__device__ __forceinline__ bf16x8 pack8s(float4 a, float4 b, float s) {
    bf16x8 w;
    w[0]=(short)f2bf(a.x*s); w[1]=(short)f2bf(a.y*s); w[2]=(short)f2bf(a.z*s); w[3]=(short)f2bf(a.w*s);
    w[4]=(short)f2bf(b.x*s); w[5]=(short)f2bf(b.y*s); w[6]=(short)f2bf(b.z*s); w[7]=(short)f2bf(b.w*s);
    return w;
}
__device__ __forceinline__ unsigned int cvtpk(float lo, float hi) {
    unsigned int r;
    asm("v_cvt_pk_bf16_f32 %0, %1, %2" : "=v"(r) : "v"(lo), "v"(hi));
    return r;
}
// hidden-unit permutation: D-reg (hb,q,r) owns hu; next-step B-fragment is lane-local.
__device__ __forceinline__ int hu_of(int hb, int q, int r) {
    return ((hb >> 1) << 5) + (q << 3) + ((hb & 1) << 2) + r;
}

// ---------- fused counting sort (desc length), one block, per-wave hists ----------
__global__ __launch_bounds__(1024) void k_sort(const int* __restrict__ lens, int U,
                                               int* __restrict__ order) {
    __shared__ int whist[16][52];
    __shared__ int base[52];
    const int tid = threadIdx.x;
    const int w = tid >> 6, l = tid & 63;
    for (int i = l; i < 52; i += 64) whist[w][i] = 0;
    __syncthreads();
    for (int u = tid; u < U; u += 1024) atomicAdd(&whist[w][lens[u]], 1);
    __syncthreads();
    if (tid < 52) {
        int s = 0;
        #pragma unroll
        for (int ww = 0; ww < 16; ++ww) s += whist[ww][tid];
        base[tid] = s;
    }
    __syncthreads();
    if (tid == 0) {  // descending-length offsets
        int s = 0;
        for (int b = 51; b >= 0; --b) { int c = base[b]; base[b] = s; s += c; }
    }
    __syncthreads();
    for (int u = tid; u < U; u += 1024) { int p = atomicAdd(&base[lens[u]], 1); order[p] = u; }
}

// ---------- barrier-free LSTM: one independent 8-user batch per wave ----------
__global__ __launch_bounds__(256, 2) void lstm_wave(
    const int* __restrict__ seq, const int* __restrict__ lens,
    const float* __restrict__ emb,
    const float* __restrict__ W_ih, const float* __restrict__ W_hh,
    const float* __restrict__ b_ih, const float* __restrict__ b_hh,
    const int* __restrict__ order,
    float* __restrict__ out_sum, float* __restrict__ cnt,
    int U, int T)
{
    // [0,32K): W_ih bf16 fragments (block-shared); [32K,48K): per-wave scatter transpose
    __shared__ __align__(16) unsigned char lds[32768 + 16384];
    const int tid  = threadIdx.x;
    const int wv   = tid >> 6;
    const int lane = tid & 63;
    const int su   = lane & 15;     // B/D column = user slot (0..7 real, 8..15 dummy)
    const int q    = lane >> 4;     // k-group / D-row group

    // ---- stage W_ih fragments to LDS, exp2 gate scale folded in ----
    for (int s = tid; s < 2048; s += 256) {
        const int rt = s >> 7, kt = (s >> 6) & 1, l = s & 63;
        const int g = rt >> 2, hb = rt & 3;
        const int rho = l & 15, qf = l >> 4;
        const float sg = (g == 2) ? S_TANH : S_SIG;
        const int grow = g * 64 + hu_of(hb, rho >> 2, rho & 3);
        const float* src = W_ih + (size_t)grow * EDIM + kt * 32 + qf * 8;
        float4 a = *reinterpret_cast<const float4*>(src);
        float4 b = *reinterpret_cast<const float4*>(src + 4);
        *reinterpret_cast<bf16x8*>(lds + (size_t)s * 16) = pack8s(a, b, sg);
    }

    // ---- W_hh fragments (exp2-scaled) + bias in registers ----
    bf16x8 wh[4][4][2];
    f32x4  biasv[4][4];
    #pragma unroll
    for (int g = 0; g < 4; ++g) {
        const float sg = (g == 2) ? S_TANH : S_SIG;
        #pragma unroll
        for (int hb = 0; hb < 4; ++hb) {
            const int grow = g * 64 + hu_of(hb, su >> 2, su & 3);
            const float* wp = W_hh + (size_t)grow * HDIM + q * 8;
            #pragma unroll
            for (int kp = 0; kp < 2; ++kp) {
                float4 c2 = *reinterpret_cast<const float4*>(wp + kp * 32);
                float4 d2 = *reinterpret_cast<const float4*>(wp + kp * 32 + 4);
                wh[g][hb][kp] = pack8s(c2, d2, sg);
            }
            #pragma unroll
            for (int r = 0; r < 4; ++r) {
                const int gi2 = g * 64 + hu_of(hb, q, r);
                biasv[g][hb][r] = sg * (b_ih[gi2] + b_hh[gi2]);
            }
        }
    }
    __syncthreads();   // W_ih staging visible (only block barrier)

    // ---- serpentine wave->group assignment (sum-balanced) ----
    const int nblk = gridDim.x;
    const int grp  = (wv & 1) ? ((wv + 1) * nblk - 1 - blockIdx.x)
                              : (wv * nblk + blockIdx.x);
    const int wbase = grp * UPW;
    int us = 0, len = 0;
    if (su < UPW && wbase + su < U) { us = order[wbase + su]; len = lens[us]; }
    const int* sp = seq + (size_t)us * T;
    int mT = len;
    mT = max(mT, __shfl_xor(mT, 1, 64));
    mT = max(mT, __shfl_xor(mT, 2, 64));
    mT = max(mT, __shfl_xor(mT, 4, 64));
    mT = max(mT, __shfl_xor(mT, 8, 64));
    if (mT <= 0) return;

    const float4* e4 = reinterpret_cast<const float4*>(emb);
    int itc = sp[0];
    int itn = (1 < mT) ? sp[1] : itc;
    bf16x8 bx0, bx1, bh0 = {0,0,0,0,0,0,0,0}, bh1 = {0,0,0,0,0,0,0,0};
    {
        const size_t eb = (size_t)itc * 16 + q * 2;
        bx0 = pack8s(e4[eb],     e4[eb + 1], 1.0f);
        bx1 = pack8s(e4[eb + 8], e4[eb + 9], 1.0f);
    }
    f32x4 cst[4] = {{0,0,0,0},{0,0,0,0},{0,0,0,0},{0,0,0,0}};
    f32x4 hs[4];              // masked h payload pending scatter (prev step)
    int   itp = 0, vprev = 0;
    const int XP = 32768 + wv * 4096;

    auto scatter_prev = [&]() {
        #pragma unroll
        for (int hb = 0; hb < 4; ++hb) {
            int byte = (su * 64 + hu_of(hb, q, 0)) * 4;
            byte ^= (su & 7) << 4;                     // bank swizzle
            *reinterpret_cast<f32x4*>(lds + XP + byte) = hs[hb];
        }
        asm volatile("s_waitcnt lgkmcnt(0)" ::: "memory");
        #pragma unroll
        for (int g = 0; g < UPW; ++g) {
            const int itg = __builtin_amdgcn_readlane(itp, g);   // lane g: su==g
            const int byte = ((g * 64 + lane) * 4) ^ ((g & 7) << 4);
            const float hv = *reinterpret_cast<const float*>(lds + XP + byte);
            atomicAdd(&out_sum[(size_t)itg * HDIM + lane], hv);  // 64 consecutive dwords
        }
        if (q == 0 && vprev) atomicAdd(&cnt[itp], 1.0f);
    };

    for (int t = 0; t < mT; ++t) {
        // ---- prefetch x(t+1), item(t+2) (h-independent) ----
        float4 na, nb, nc, nd; int sn = itn;
        const bool pf = (t + 1 < mT);
        if (pf) {
            const size_t eb = (size_t)itn * 16 + q * 2;
            na = e4[eb]; nb = e4[eb + 1]; nc = e4[eb + 8]; nd = e4[eb + 9];
        }
        if (t + 2 < mT) sn = sp[t + 2];

        // ---- scatter previous step (fire-and-forget atomics) ----
        if (t > 0) scatter_prev();

        // ---- MFMA gates + nonlinearity, per hb row-block ----
        f32x4 hn[4];
        #pragma unroll
        for (int hb = 0; hb < 4; ++hb) {
            bf16x8 wx0[4], wx1[4];
            #pragma unroll
            for (int g = 0; g < 4; ++g) {
                const int rt = g * 4 + hb;
                wx0[g] = *reinterpret_cast<const bf16x8*>(lds + ((rt * 2 + 0) * 64 + lane) * 16);
                wx1[g] = *reinterpret_cast<const bf16x8*>(lds + ((rt * 2 + 1) * 64 + lane) * 16);
            }
            f32x4 acc[4];
            #pragma unroll
            for (int g = 0; g < 4; ++g) {
                acc[g] = biasv[g][hb];
                acc[g] = __builtin_amdgcn_mfma_f32_16x16x32_bf16(wx0[g], bx0, acc[g], 0, 0, 0);
                acc[g] = __builtin_amdgcn_mfma_f32_16x16x32_bf16(wx1[g], bx1, acc[g], 0, 0, 0);
                acc[g] = __builtin_amdgcn_mfma_f32_16x16x32_bf16(wh[g][hb][0], bh0, acc[g], 0, 0, 0);
                acc[g] = __builtin_amdgcn_mfma_f32_16x16x32_bf16(wh[g][hb][1], bh1, acc[g], 0, 0, 0);
            }
            #pragma unroll
            for (int r = 0; r < 4; ++r) {           // pre-acts already exp2-scaled
                const float gi = rcp_(1.0f + exp2_(acc[0][r]));
                const float gf = rcp_(1.0f + exp2_(acc[1][r]));
                const float gg = 1.0f - 2.0f * rcp_(1.0f + exp2_(acc[2][r]));
                const float go = rcp_(1.0f + exp2_(acc[3][r]));
                const float cc = gf * cst[hb][r] + gi * gg;
                cst[hb][r] = cc;
                const float th = 1.0f - 2.0f * rcp_(1.0f + exp2_(S_TANH * cc));
                hn[hb][r] = go * th;
            }
        }
        // ---- pack next-step h B-fragments (lane-local via hu permutation) ----
        uint4 p0, p1;
        p0.x = cvtpk(hn[0][0], hn[0][1]); p0.y = cvtpk(hn[0][2], hn[0][3]);
        p0.z = cvtpk(hn[1][0], hn[1][1]); p0.w = cvtpk(hn[1][2], hn[1][3]);
        p1.x = cvtpk(hn[2][0], hn[2][1]); p1.y = cvtpk(hn[2][2], hn[2][3]);
        p1.z = cvtpk(hn[3][0], hn[3][1]); p1.w = cvtpk(hn[3][2], hn[3][3]);
        bh0 = __builtin_bit_cast(bf16x8, p0);
        bh1 = __builtin_bit_cast(bf16x8, p1);

        // ---- save scatter state (mask invalid steps to 0) ----
        const int val = (t < len) ? 1 : 0;
        const float vm = val ? 1.0f : 0.0f;
        #pragma unroll
        for (int hb = 0; hb < 4; ++hb)
            #pragma unroll
            for (int r = 0; r < 4; ++r) hs[hb][r] = hn[hb][r] * vm;
        itp = itc; vprev = val;

        // ---- rotate pipeline ----
        if (pf) { bx0 = pack8s(na, nb, 1.0f); bx1 = pack8s(nc, nd, 1.0f); itc = itn; itn = sn; }
    }
    scatter_prev();   // epilogue: last step's h
}

__global__ __launch_bounds__(256) void finalize_mean(
    float* __restrict__ out, const float* __restrict__ cnt, int NI)
{
    const int idx = blockIdx.x * blockDim.x + threadIdx.x;
    const int total = NI * (HDIM / 4);
    if (idx >= total) return;
    const int i = idx >> 4;
    const float c = cnt[i];
    const float s = (c > 0.0f) ? __builtin_amdgcn_rcpf(c) : 0.0f;
    float4* o = reinterpret_cast<float4*>(out);
    float4 v = o[idx];
    v.x *= s; v.y *= s; v.z *= s; v.w *= s;
    o[idx] = v;
}

extern "C" void kernel_launch(void* const* d_in, const int* in_sizes, int n_in,
                              void* d_out, int out_size, void* d_ws, size_t ws_size,
                              hipStream_t stream)
{
    const int*   seq  = (const int*)d_in[0];
    const int*   lens = (const int*)d_in[1];
    const float* emb  = (const float*)d_in[2];
    const float* W_ih = (const float*)d_in[3];
    const float* W_hh = (const float*)d_in[4];
    const float* b_ih = (const float*)d_in[5];
    const float* b_hh = (const float*)d_in[6];
    float* out = (float*)d_out;

    const int U  = in_sizes[1];
    const int T  = in_sizes[0] / U;
    const int NI = in_sizes[2] / EDIM;

    // ws layout: cnt[NI] f32 | order[U] i32
    float* cnt   = (float*)d_ws;
    int*   order = (int*)d_ws + NI;

    hipMemsetAsync(out, 0, (size_t)NI * HDIM * sizeof(float), stream);
    hipMemsetAsync(cnt, 0, (size_t)NI * sizeof(float), stream);

    k_sort<<<1, 1024, 0, stream>>>(lens, U, order);

    const int nblk = (U + 4 * UPW - 1) / (4 * UPW);   // 512 blocks: 2/CU, 2 waves/SIMD
    lstm_wave<<<nblk, 256, 0, stream>>>(seq, lens, emb, W_ih, W_hh, b_ih, b_hh,
                                        order, out, cnt, U, T);

    const int total = NI * (HDIM / 4);
    finalize_mean<<<(total + 255) / 256, 256, 0, stream>>>(out, cnt, NI);
}

// Round 9
// 363.785 us; speedup vs baseline: 1.3199x; 1.3199x over previous
//
#include <hip/hip_runtime.h>

#define EDIM 64
#define HDIM 64
#define S_SIG  (-1.4426950408889634f)
#define S_TANH ( 2.8853900817779268f)
#define UPW 8     // users per wave (8 -> 2048 waves -> 2 waves/SIMD)

typedef short bf16x8 __attribute__((ext_vector_type(8)));
typedef float f32x4  __attribute__((ext_vector_type(4)));

__device__ __forceinline__ float rcp_(float x){ return __builtin_amdgcn_rcpf(x); }
__device__ __forceinline__ float exp2_(float x){ return __builtin_amdgcn_exp2f(x); }
__device__ __forceinline__ unsigned short f2bf(float f) {   // RNE
    unsigned int u = __float_as_uint(f);
    return (unsigned short)((u + 0x7FFF + ((u >> 16) & 1)) >> 16);
}
__device__ __forceinline__ bf16x8 pack8s(float4 a, float4 b, float s) {
    bf16x8 w;
    w[0]=(short)f2bf(a.x*s); w[1]=(short)f2bf(a.y*s); w[2]=(short)f2bf(a.z*s); w[3]=(short)f2bf(a.w*s);
    w[4]=(short)f2bf(b.x*s); w[5]=(short)f2bf(b.y*s); w[6]=(short)f2bf(b.z*s); w[7]=(short)f2bf(b.w*s);
    return w;
}
__device__ __forceinline__ unsigned int cvtpk(float lo, float hi) {
    unsigned int r;
    asm("v_cvt_pk_bf16_f32 %0, %1, %2" : "=v"(r) : "v"(lo), "v"(hi));
    return r;
}
// hidden-unit permutation: D-reg (hb,q,r) owns hu; next-step B-fragment is lane-local.
__device__ __forceinline__ int hu_of(int hb, int q, int r) {
    return ((hb >> 1) << 5) + (q << 3) + ((hb & 1) << 2) + r;
}

// ---------- fused counting sort (desc length), one block, per-wave hists ----------
__global__ __launch_bounds__(1024) void k_sort(const int* __restrict__ lens, int U,
                                               int* __restrict__ order) {
    __shared__ int whist[16][52];
    __shared__ int base[52];
    const int tid = threadIdx.x;
    const int w = tid >> 6, l = tid & 63;
    for (int i = l; i < 52; i += 64) whist[w][i] = 0;
    __syncthreads();
    for (int u = tid; u < U; u += 1024) atomicAdd(&whist[w][lens[u]], 1);
    __syncthreads();
    if (tid < 52) {
        int s = 0;
        #pragma unroll
        for (int ww = 0; ww < 16; ++ww) s += whist[ww][tid];
        base[tid] = s;
    }
    __syncthreads();
    if (tid == 0) {  // descending-length offsets
        int s = 0;
        for (int b = 51; b >= 0; --b) { int c = base[b]; base[b] = s; s += c; }
    }
    __syncthreads();
    for (int u = tid; u < U; u += 1024) { int p = atomicAdd(&base[lens[u]], 1); order[p] = u; }
}

// ---------- barrier-free LSTM: one independent 8-user batch per wave ----------
// launch_bounds(256,1): do NOT cap registers for occupancy — demand ~220 fits
// <=256, and HW then gives 2 waves/SIMD naturally (occupancy halves above 256).
__global__ __launch_bounds__(256, 1) void lstm_wave(
    const int* __restrict__ seq, const int* __restrict__ lens,
    const float* __restrict__ emb,
    const float* __restrict__ W_ih, const float* __restrict__ W_hh,
    const float* __restrict__ b_ih, const float* __restrict__ b_hh,
    const int* __restrict__ order,
    float* __restrict__ out_sum, float* __restrict__ cnt,
    int U, int T)
{
    // [0,32K): W_ih bf16 fragments (block-shared); [32K,48K): per-wave scatter transpose
    __shared__ __align__(16) unsigned char lds[32768 + 16384];
    const int tid  = threadIdx.x;
    const int wv   = tid >> 6;
    const int lane = tid & 63;
    const int su   = lane & 15;     // B/D column = user slot (0..7 real, 8..15 dummy)
    const int q    = lane >> 4;     // k-group / D-row group

    // ---- stage W_ih fragments to LDS, exp2 gate scale folded in ----
    for (int s = tid; s < 2048; s += 256) {
        const int rt = s >> 7, kt = (s >> 6) & 1, l = s & 63;
        const int g = rt >> 2, hb = rt & 3;
        const int rho = l & 15, qf = l >> 4;
        const float sg = (g == 2) ? S_TANH : S_SIG;
        const int grow = g * 64 + hu_of(hb, rho >> 2, rho & 3);
        const float* src = W_ih + (size_t)grow * EDIM + kt * 32 + qf * 8;
        float4 a = *reinterpret_cast<const float4*>(src);
        float4 b = *reinterpret_cast<const float4*>(src + 4);
        *reinterpret_cast<bf16x8*>(lds + (size_t)s * 16) = pack8s(a, b, sg);
    }

    // ---- W_hh fragments (exp2-scaled) + bias in registers ----
    bf16x8 wh[4][4][2];
    f32x4  biasv[4][4];
    #pragma unroll
    for (int g = 0; g < 4; ++g) {
        const float sg = (g == 2) ? S_TANH : S_SIG;
        #pragma unroll
        for (int hb = 0; hb < 4; ++hb) {
            const int grow = g * 64 + hu_of(hb, su >> 2, su & 3);
            const float* wp = W_hh + (size_t)grow * HDIM + q * 8;
            #pragma unroll
            for (int kp = 0; kp < 2; ++kp) {
                float4 c2 = *reinterpret_cast<const float4*>(wp + kp * 32);
                float4 d2 = *reinterpret_cast<const float4*>(wp + kp * 32 + 4);
                wh[g][hb][kp] = pack8s(c2, d2, sg);
            }
            #pragma unroll
            for (int r = 0; r < 4; ++r) {
                const int gi2 = g * 64 + hu_of(hb, q, r);
                biasv[g][hb][r] = sg * (b_ih[gi2] + b_hh[gi2]);
            }
        }
    }
    __syncthreads();   // W_ih staging visible (only block barrier)

    // ---- serpentine wave->group assignment (sum-balanced) ----
    const int nblk = gridDim.x;
    const int grp  = (wv & 1) ? ((wv + 1) * nblk - 1 - blockIdx.x)
                              : (wv * nblk + blockIdx.x);
    const int wbase = grp * UPW;
    // dummy lanes (su>=UPW) alias slot su&7's user: their gathers duplicate
    // real lanes' rows (L1 hits) instead of wandering off to global user 0.
    const int slot = su & (UPW - 1);
    int us = 0, len = 0;
    if (wbase + slot < U) us = order[wbase + slot];
    if (su < UPW && wbase + su < U) len = lens[us];
    const int* sp = seq + (size_t)us * T;
    int mT = len;
    mT = max(mT, __shfl_xor(mT, 1, 64));
    mT = max(mT, __shfl_xor(mT, 2, 64));
    mT = max(mT, __shfl_xor(mT, 4, 64));
    mT = max(mT, __shfl_xor(mT, 8, 64));
    if (mT <= 0) return;

    const float4* e4 = reinterpret_cast<const float4*>(emb);
    int itc = sp[0];
    int itn = (1 < mT) ? sp[1] : itc;
    bf16x8 bx0, bx1, bh0 = {0,0,0,0,0,0,0,0}, bh1 = {0,0,0,0,0,0,0,0};
    {
        const size_t eb = (size_t)itc * 16 + q * 2;
        bx0 = pack8s(e4[eb],     e4[eb + 1], 1.0f);
        bx1 = pack8s(e4[eb + 8], e4[eb + 9], 1.0f);
    }
    f32x4 cst[4] = {{0,0,0,0},{0,0,0,0},{0,0,0,0},{0,0,0,0}};
    f32x4 hs[4];              // masked h payload pending scatter (prev step)
    int   itp = 0, vprev = 0;
    const int XP = 32768 + wv * 4096;

    auto scatter_prev = [&]() {
        #pragma unroll
        for (int hb = 0; hb < 4; ++hb) {
            int byte = (su * 64 + hu_of(hb, q, 0)) * 4;
            byte ^= (su & 7) << 4;                     // bank swizzle
            *reinterpret_cast<f32x4*>(lds + XP + byte) = hs[hb];
        }
        asm volatile("s_waitcnt lgkmcnt(0)" ::: "memory");
        #pragma unroll
        for (int g = 0; g < UPW; ++g) {
            const int itg = __builtin_amdgcn_readlane(itp, g);   // lane g: su==g
            const int byte = ((g * 64 + lane) * 4) ^ ((g & 7) << 4);
            const float hv = *reinterpret_cast<const float*>(lds + XP + byte);
            atomicAdd(&out_sum[(size_t)itg * HDIM + lane], hv);  // 64 consecutive dwords
        }
        if (q == 0 && vprev) atomicAdd(&cnt[itp], 1.0f);
    };

    for (int t = 0; t < mT; ++t) {
        // ---- prefetch x(t+1), item(t+2) (h-independent) ----
        float4 na, nb, nc, nd; int sn = itn;
        const bool pf = (t + 1 < mT);
        if (pf) {
            const size_t eb = (size_t)itn * 16 + q * 2;
            na = e4[eb]; nb = e4[eb + 1]; nc = e4[eb + 8]; nd = e4[eb + 9];
        }
        if (t + 2 < mT) sn = sp[t + 2];

        // ---- scatter previous step (fire-and-forget atomics) ----
        if (t > 0) scatter_prev();

        // ---- MFMA gates + nonlinearity, per hb row-block ----
        f32x4 hn[4];
        #pragma unroll
        for (int hb = 0; hb < 4; ++hb) {
            bf16x8 wx0[4], wx1[4];
            #pragma unroll
            for (int g = 0; g < 4; ++g) {
                const int rt = g * 4 + hb;
                wx0[g] = *reinterpret_cast<const bf16x8*>(lds + ((rt * 2 + 0) * 64 + lane) * 16);
                wx1[g] = *reinterpret_cast<const bf16x8*>(lds + ((rt * 2 + 1) * 64 + lane) * 16);
            }
            f32x4 acc[4];
            #pragma unroll
            for (int g = 0; g < 4; ++g) {
                acc[g] = biasv[g][hb];
                acc[g] = __builtin_amdgcn_mfma_f32_16x16x32_bf16(wx0[g], bx0, acc[g], 0, 0, 0);
                acc[g] = __builtin_amdgcn_mfma_f32_16x16x32_bf16(wx1[g], bx1, acc[g], 0, 0, 0);
                acc[g] = __builtin_amdgcn_mfma_f32_16x16x32_bf16(wh[g][hb][0], bh0, acc[g], 0, 0, 0);
                acc[g] = __builtin_amdgcn_mfma_f32_16x16x32_bf16(wh[g][hb][1], bh1, acc[g], 0, 0, 0);
            }
            #pragma unroll
            for (int r = 0; r < 4; ++r) {           // pre-acts already exp2-scaled
                const float gi = rcp_(1.0f + exp2_(acc[0][r]));
                const float gf = rcp_(1.0f + exp2_(acc[1][r]));
                const float gg = 1.0f - 2.0f * rcp_(1.0f + exp2_(acc[2][r]));
                const float go = rcp_(1.0f + exp2_(acc[3][r]));
                const float cc = gf * cst[hb][r] + gi * gg;
                cst[hb][r] = cc;
                const float th = 1.0f - 2.0f * rcp_(1.0f + exp2_(S_TANH * cc));
                hn[hb][r] = go * th;
            }
        }
        // ---- pack next-step h B-fragments (lane-local via hu permutation) ----
        uint4 p0, p1;
        p0.x = cvtpk(hn[0][0], hn[0][1]); p0.y = cvtpk(hn[0][2], hn[0][3]);
        p0.z = cvtpk(hn[1][0], hn[1][1]); p0.w = cvtpk(hn[1][2], hn[1][3]);
        p1.x = cvtpk(hn[2][0], hn[2][1]); p1.y = cvtpk(hn[2][2], hn[2][3]);
        p1.z = cvtpk(hn[3][0], hn[3][1]); p1.w = cvtpk(hn[3][2], hn[3][3]);
        bh0 = __builtin_bit_cast(bf16x8, p0);
        bh1 = __builtin_bit_cast(bf16x8, p1);

        // ---- save scatter state (mask invalid steps to 0) ----
        const int val = (t < len) ? 1 : 0;
        const float vm = val ? 1.0f : 0.0f;
        #pragma unroll
        for (int hb = 0; hb < 4; ++hb)
            #pragma unroll
            for (int r = 0; r < 4; ++r) hs[hb][r] = hn[hb][r] * vm;
        itp = itc; vprev = val;

        // ---- rotate pipeline ----
        if (pf) { bx0 = pack8s(na, nb, 1.0f); bx1 = pack8s(nc, nd, 1.0f); itc = itn; itn = sn; }
    }
    scatter_prev();   // epilogue: last step's h
}

__global__ __launch_bounds__(256) void finalize_mean(
    float* __restrict__ out, const float* __restrict__ cnt, int NI)
{
    const int idx = blockIdx.x * blockDim.x + threadIdx.x;
    const int total = NI * (HDIM / 4);
    if (idx >= total) return;
    const int i = idx >> 4;
    const float c = cnt[i];
    const float s = (c > 0.0f) ? __builtin_amdgcn_rcpf(c) : 0.0f;
    float4* o = reinterpret_cast<float4*>(out);
    float4 v = o[idx];
    v.x *= s; v.y *= s; v.z *= s; v.w *= s;
    o[idx] = v;
}

extern "C" void kernel_launch(void* const* d_in, const int* in_sizes, int n_in,
                              void* d_out, int out_size, void* d_ws, size_t ws_size,
                              hipStream_t stream)
{
    const int*   seq  = (const int*)d_in[0];
    const int*   lens = (const int*)d_in[1];
    const float* emb  = (const float*)d_in[2];
    const float* W_ih = (const float*)d_in[3];
    const float* W_hh = (const float*)d_in[4];
    const float* b_ih = (const float*)d_in[5];
    const float* b_hh = (const float*)d_in[6];
    float* out = (float*)d_out;

    const int U  = in_sizes[1];
    const int T  = in_sizes[0] / U;
    const int NI = in_sizes[2] / EDIM;

    // ws layout: cnt[NI] f32 | order[U] i32
    float* cnt   = (float*)d_ws;
    int*   order = (int*)d_ws + NI;

    hipMemsetAsync(out, 0, (size_t)NI * HDIM * sizeof(float), stream);
    hipMemsetAsync(cnt, 0, (size_t)NI * sizeof(float), stream);

    k_sort<<<1, 1024, 0, stream>>>(lens, U, order);

    const int nblk = (U + 4 * UPW - 1) / (4 * UPW);   // 512 blocks: 2/CU, 2 waves/SIMD
    lstm_wave<<<nblk, 256, 0, stream>>>(seq, lens, emb, W_ih, W_hh, b_ih, b_hh,
                                        order, out, cnt, U, T);

    const int total = NI * (HDIM / 4);
    finalize_mean<<<(total + 255) / 256, 256, 0, stream>>>(out, cnt, NI);
}